// Round 1
// baseline (1906.179 us; speedup 1.0000x reference)
//
#include <hip/hip_runtime.h>
#include <hip/hip_bf16.h>

// Problem constants
#define TT 2048
#define KK 6
#define EE 32
#define DD 2048
#define FF 1408
#define SS 2
#define CC 384   // TT*KK/EE

typedef __bf16 bf16_t;
typedef __attribute__((ext_vector_type(8))) __bf16 bf16x8;
typedef __attribute__((ext_vector_type(4))) float f32x4;
typedef unsigned int u32;

__device__ __forceinline__ u32 f2bf(float f) {
    u32 u = __builtin_bit_cast(u32, f);
    return (u + 0x7fffu + ((u >> 16) & 1u)) >> 16;   // RNE, no NaN in data
}
__device__ __forceinline__ u32 pack2(float a, float b) {
    return f2bf(a) | (f2bf(b) << 16);
}

// ---------------- dispatch: pair -> slot (balanced: exactly CC per expert) ----
__global__ void k_dispatch(const int* __restrict__ idx, int* __restrict__ counts,
                           int* __restrict__ tok, int* __restrict__ sop) {
    int p = blockIdx.x * 256 + threadIdx.x;
    if (p >= TT * KK) return;
    int e = idx[p];
    int pos = atomicAdd(&counts[e], 1);
    int slot = e * CC + pos;
    tok[slot] = p / KK;
    sop[p] = slot;
}

// ---------------- gather + fp32->bf16 convert --------------------------------
// rows [0, EE*CC): gathered routed inputs; rows [EE*CC, EE*CC+TT): x copy (shared)
__global__ void k_gather(const float* __restrict__ x, const int* __restrict__ tok,
                         bf16_t* __restrict__ xall) {
    int row = blockIdx.x;
    int srow = (row < EE * CC) ? tok[row] : (row - EE * CC);
    const float* src = x + (size_t)srow * DD;
    bf16_t* dst = xall + (size_t)row * DD;
    int c0 = threadIdx.x * 8;
    float4 a = *(const float4*)(src + c0);
    float4 b = *(const float4*)(src + c0 + 4);
    uint4 o;
    o.x = pack2(a.x, a.y); o.y = pack2(a.z, a.w);
    o.z = pack2(b.x, b.y); o.w = pack2(b.z, b.w);
    *(uint4*)(dst + c0) = o;
}

// ---------------- grouped GEMM: Out[bf16] = A[bf16] * B[fp32->bf16] ----------
// 128x128 tile, BK=32, 4 waves (2x2), 16x16x32 bf16 MFMA, 4x4 frags/wave.
// A staged via global_load_lds (16B); B converted in-reg and stored transposed
// to LDS [n][k] with row stride 40 elems (80B, 16B aligned).
#define BSTR 40
__global__ __launch_bounds__(256) void k_gemm(
    const bf16_t* __restrict__ Aall, const float* __restrict__ Br,
    const float* __restrict__ Bsh, bf16_t* __restrict__ Out,
    int Kdim, int N, int ash_stride)
{
    int g = blockIdx.z;
    size_t arow, orow; const float* Bp; int mtiles;
    if (g < EE) {
        arow = (size_t)g * CC; orow = arow;
        Bp = Br + (size_t)g * Kdim * N; mtiles = CC / 128;
    } else {
        int s = g - EE;
        arow = (size_t)EE * CC + (size_t)s * ash_stride;
        orow = (size_t)EE * CC + (size_t)s * TT;
        Bp = Bsh + (size_t)s * Kdim * N; mtiles = TT / 128;
    }
    if ((int)blockIdx.y >= mtiles) return;

    const bf16_t* A = Aall + (arow + (size_t)blockIdx.y * 128) * Kdim;
    bf16_t* Cout = Out + (orow + (size_t)blockIdx.y * 128) * N + (size_t)blockIdx.x * 128;
    Bp += (size_t)blockIdx.x * 128;

    __shared__ __align__(16) bf16_t As[128 * 32];
    __shared__ __align__(16) bf16_t Bs[128 * BSTR];

    const int tid = threadIdx.x;
    const int lane = tid & 63, wid = tid >> 6;
    const int m_off = (wid >> 1) * 64, n_off = (wid & 1) * 64;
    const int l15 = lane & 15, lq = lane >> 4;

    f32x4 acc[4][4] = {};

    const int arow0 = tid >> 2;          // 0..63
    const int acol  = (tid & 3) * 8;
    const int bn = tid & 127, kb = (tid >> 7) * 16;

    const int ksteps = Kdim >> 5;
    for (int kt = 0; kt < ksteps; ++kt) {
        const int k0 = kt << 5;
        // --- A tile 128x32 via async global->LDS, width 16 ---
        {
            const bf16_t* g0 = A + (size_t)arow0 * Kdim + (k0 + acol);
            const bf16_t* g1 = A + (size_t)(arow0 + 64) * Kdim + (k0 + acol);
            auto l0 = (__attribute__((address_space(3))) u32*)(void*)(As + (size_t)(wid * 64) * 8);
            auto l1 = (__attribute__((address_space(3))) u32*)(void*)(As + (size_t)(256 + wid * 64) * 8);
            __builtin_amdgcn_global_load_lds((const __attribute__((address_space(1))) u32*)(const void*)g0, l0, 16, 0, 0);
            __builtin_amdgcn_global_load_lds((const __attribute__((address_space(1))) u32*)(const void*)g1, l1, 16, 0, 0);
        }
        // --- B tile 32x128 fp32: coalesced load, cvt->bf16, transposed LDS write ---
        {
            const float* bg = Bp + (size_t)(k0 + kb) * N + bn;
            float v[16];
            #pragma unroll
            for (int j = 0; j < 16; ++j) v[j] = bg[(size_t)j * N];
            u32 p[8];
            #pragma unroll
            for (int j = 0; j < 8; ++j) p[j] = pack2(v[2 * j], v[2 * j + 1]);
            uint4 w0, w1;
            w0.x = p[0]; w0.y = p[1]; w0.z = p[2]; w0.w = p[3];
            w1.x = p[4]; w1.y = p[5]; w1.z = p[6]; w1.w = p[7];
            *(uint4*)(Bs + (size_t)bn * BSTR + kb) = w0;
            *(uint4*)(Bs + (size_t)bn * BSTR + kb + 8) = w1;
        }
        __syncthreads();
        bf16x8 af[4], bfr[4];
        #pragma unroll
        for (int i = 0; i < 4; ++i)
            af[i] = *(const bf16x8*)(As + (size_t)(m_off + i * 16 + l15) * 32 + lq * 8);
        #pragma unroll
        for (int j = 0; j < 4; ++j)
            bfr[j] = *(const bf16x8*)(Bs + (size_t)(n_off + j * 16 + l15) * BSTR + lq * 8);
        #pragma unroll
        for (int i = 0; i < 4; ++i)
            #pragma unroll
            for (int j = 0; j < 4; ++j)
                acc[i][j] = __builtin_amdgcn_mfma_f32_16x16x32_bf16(af[i], bfr[j], acc[i][j], 0, 0, 0);
        __syncthreads();
    }

    // epilogue: C/D layout col=lane&15, row=quad*4+reg
    #pragma unroll
    for (int i = 0; i < 4; ++i) {
        #pragma unroll
        for (int j = 0; j < 4; ++j) {
            int n = n_off + j * 16 + l15;
            #pragma unroll
            for (int r = 0; r < 4; ++r) {
                int m = m_off + i * 16 + lq * 4 + r;
                Cout[(size_t)m * N + n] = (bf16_t)acc[i][j][r];
            }
        }
    }
}

// ---------------- silu(gate) * up ------------------------------------------
__global__ void k_silu(const bf16_t* __restrict__ gu, bf16_t* __restrict__ act) {
    u32 f = ((u32)blockIdx.x * 256 + threadIdx.x) * 8;
    u32 row = f / FF;
    u32 col = f % FF;
    const bf16_t* base = gu + (size_t)row * (2 * FF) + col;
    bf16x8 g = *(const bf16x8*)(base);
    bf16x8 u = *(const bf16x8*)(base + FF);
    bf16x8 ov;
    #pragma unroll
    for (int j = 0; j < 8; ++j) {
        float gf = (float)g[j], uf = (float)u[j];
        float s = gf / (1.0f + __expf(-gf));
        ov[j] = (bf16_t)(s * uf);
    }
    *(bf16x8*)(act + (size_t)row * FF + col) = ov;
}

// ---------------- combine: weighted scatter of routed + shared add ----------
__global__ void k_combine(const bf16_t* __restrict__ down, const int* __restrict__ sop,
                          const float* __restrict__ wts, float* __restrict__ y) {
    int t = blockIdx.x;
    int d0 = threadIdx.x * 8;
    float a[8] = {0, 0, 0, 0, 0, 0, 0, 0};
    #pragma unroll
    for (int k = 0; k < KK; ++k) {
        int slot = sop[t * KK + k];
        float w = wts[t * KK + k];
        bf16x8 v = *(const bf16x8*)(down + (size_t)slot * DD + d0);
        #pragma unroll
        for (int j = 0; j < 8; ++j) a[j] += w * (float)v[j];
    }
    #pragma unroll
    for (int s = 0; s < SS; ++s) {
        bf16x8 v = *(const bf16x8*)(down + ((size_t)EE * CC + (size_t)s * TT + t) * DD + d0);
        #pragma unroll
        for (int j = 0; j < 8; ++j) a[j] += (float)v[j];
    }
    float4 o0, o1;
    o0.x = a[0]; o0.y = a[1]; o0.z = a[2]; o0.w = a[3];
    o1.x = a[4]; o1.y = a[5]; o1.z = a[6]; o1.w = a[7];
    *(float4*)(y + (size_t)t * DD + d0) = o0;
    *(float4*)(y + (size_t)t * DD + d0 + 4) = o1;
}

extern "C" void kernel_launch(void* const* d_in, const int* in_sizes, int n_in,
                              void* d_out, int out_size, void* d_ws, size_t ws_size,
                              hipStream_t stream) {
    (void)in_sizes; (void)n_in; (void)out_size; (void)ws_size;
    const float* x      = (const float*)d_in[0];
    const float* wts    = (const float*)d_in[1];
    const float* w_gu   = (const float*)d_in[2];
    const float* w_dn   = (const float*)d_in[3];
    const float* w_gu_s = (const float*)d_in[4];
    const float* w_dn_s = (const float*)d_in[5];
    const int*   indices= (const int*)d_in[6];
    float* y = (float*)d_out;

    char* ws = (char*)d_ws;
    size_t off = 0;
    auto alloc = [&](size_t bytes) {
        void* p = ws + off;
        off = (off + bytes + 255) & ~(size_t)255;
        return p;
    };
    int*    counts = (int*)alloc((size_t)EE * 4);
    int*    tok    = (int*)alloc((size_t)EE * CC * 4);
    int*    sop    = (int*)alloc((size_t)TT * KK * 4);
    bf16_t* xall   = (bf16_t*)alloc((size_t)(EE * CC + TT) * DD * 2);
    bf16_t* gu     = (bf16_t*)alloc((size_t)(EE * CC + SS * TT) * 2 * FF * 2);
    bf16_t* actb   = (bf16_t*)alloc((size_t)(EE * CC + SS * TT) * FF * 2);
    bf16_t* dnout  = (bf16_t*)alloc((size_t)(EE * CC + SS * TT) * DD * 2);

    hipMemsetAsync(counts, 0, EE * 4, stream);
    k_dispatch<<<(TT * KK + 255) / 256, 256, 0, stream>>>(indices, counts, tok, sop);
    k_gather<<<EE * CC + TT, 256, 0, stream>>>(x, tok, xall);
    // gate_up: K=DD, N=2*FF; shared groups reuse the same A rows (ash_stride=0)
    k_gemm<<<dim3(2 * FF / 128, TT / 128, EE + SS), 256, 0, stream>>>(
        xall, w_gu, w_gu_s, gu, DD, 2 * FF, 0);
    k_silu<<<(EE * CC + SS * TT) * FF / 8 / 256, 256, 0, stream>>>(gu, actb);
    // down: K=FF, N=DD; shared groups have distinct A rows (ash_stride=TT)
    k_gemm<<<dim3(DD / 128, TT / 128, EE + SS), 256, 0, stream>>>(
        actb, w_dn, w_dn_s, dnout, FF, DD, TT);
    k_combine<<<TT, 256, 0, stream>>>(dnout, sop, wts, y);
}